// Round 7
// baseline (110.905 us; speedup 1.0000x reference)
//
#include <hip/hip_runtime.h>
#include <math.h>

// N_PTS=1e6, K_DIM=3, N_BINS=21; wv row = 43 floats (v_tilde[22] | w_tilde[21])
#define NROWS    3000000
#define NPTS     1000000
#define NBINS    21
#define NV       22
#define DROW     43
#define RPW      63                          // rows per wave = 21 whole points
#define NWAVES   ((NROWS + RPW - 1) / RPW)   // 47620 (last wave: 3 rows)
#define WPB      4                           // 256 threads
#define NBLK     ((NWAVES + WPB - 1) / WPB)  // 11905

// 4-byte-aligned float4: rows are 172 B apart (not 16B-aligned)
typedef float f4a4 __attribute__((ext_vector_type(4), aligned(4)));

__global__ __launch_bounds__(256, 4) void pwquad_kernel(
    const float* __restrict__ y,
    const float* __restrict__ wv,
    float* __restrict__ out)
{
    const int lane = threadIdx.x & 63;
    const int gw   = blockIdx.x * WPB + (threadIdx.x >> 6);
    const int row  = gw * RPW + lane;
    const bool active = (lane < RPW) && (row < NROWS);
    const float EPSF = 1.1920929e-07f;   // np.finfo(float32).eps

    float ltv = 0.f;

    if (active) {
        // ---- Direct per-row load: 11 overlapping 4B-aligned float4 loads.
        // All issue back-to-back; cross-lane same-line requests merge in L1/MSHR.
        const float* rp = wv + (size_t)row * DROW;
        f4a4 r[11];
#pragma unroll
        for (int i = 0; i < 10; ++i)
            r[i] = *reinterpret_cast<const f4a4*>(rp + 4 * i);   // floats 0..39
        r[10] = *reinterpret_cast<const f4a4*>(rp + 39);          // floats 39..42

        float in[43];
#pragma unroll
        for (int i = 0; i < 10; ++i)
#pragma unroll
            for (int j = 0; j < 4; ++j) in[4 * i + j] = r[i][j];
        in[40] = r[10][1]; in[41] = r[10][2]; in[42] = r[10][3];

        const float yv = y[row];   // coalesced scalar load

        // w = exp(w_tilde); normalize
        float w[NBINS];
        float wnorm = 0.f;
#pragma unroll
        for (int j = 0; j < NBINS; ++j) { w[j] = __expf(in[NV + j]); wnorm += w[j]; }
        const float invw = 1.0f / wnorm;
#pragma unroll
        for (int j = 0; j < NBINS; ++j) w[j] *= invw;

        // ve = exp(v_tilde); trapezoid normalization
        float v[NV];
#pragma unroll
        for (int i = 0; i < NV; ++i) v[i] = __expf(in[i]);
        float T = 0.f;
#pragma unroll
        for (int j = 0; j < NBINS; ++j) T += (v[j] + v[j + 1]) * 0.5f * w[j];
        const float invT = 1.0f / T;
#pragma unroll
        for (int i = 0; i < NV; ++i) v[i] = fmaxf(v[i] * invT, 1e-6f);

        // Edge search: latch last k with vw_k <= y (vw non-decreasing)
        float vw = 0.f, wsum = 0.f;
        float vwe = 0.f, wse = 0.f;
        float v0 = v[0], v1 = v[1], we = w[0];
#pragma unroll
        for (int j = 0; j < 20; ++j) {
            const float inc = (v[j] + v[j + 1]) * 0.5f * w[j];
            vw += inc;
            wsum += w[j];
            const bool q = (vw <= yv);
            vwe = q ? vw       : vwe;
            wse = q ? wsum     : wse;
            v0  = q ? v[j + 1] : v0;
            v1  = q ? v[j + 2] : v1;
            we  = q ? w[j + 1] : we;
        }

        // Quadratic solve
        float a = (v1 - v0) * we;
        const float bq = v0 * we;
        const float cc = vwe - yv;
        a = (fabsf(a) < EPSF) ? EPSF : a;
        const float dd = fmaxf(bq * bq - 2.0f * a * cc, 0.f);
        const float sq = sqrtf(dd);
        const float sol1 = (-bq - sq) / a;
        const float sol2 = (-bq + sq) / a;
        float sol = (sol1 >= 0.f && sol1 < 1.f) ? sol1 : sol2;
        sol = fminf(fmaxf(sol, EPSF), 1.f - EPSF);
        float x = we * sol + wse;
        x = fminf(fmaxf(x, EPSF), 1.f - EPSF);

        out[row] = x;
        ltv = __logf(v0 + (v1 - v0) * sol);
    }

    // logj: intra-wave shuffle (all lanes execute; inactive contribute nothing)
    const float t1 = __shfl(ltv, (lane + 1) & 63);
    const float t2 = __shfl(ltv, (lane + 2) & 63);
    if (active && (lane % 3) == 0) {
        out[NROWS + row / 3] = -(ltv + t1 + t2);   // row%3==0 -> point = row/3
    }
}

extern "C" void kernel_launch(void* const* d_in, const int* in_sizes, int n_in,
                              void* d_out, int out_size, void* d_ws, size_t ws_size,
                              hipStream_t stream) {
    const float* y  = (const float*)d_in[0];
    const float* wv = (const float*)d_in[1];
    float* out = (float*)d_out;

    pwquad_kernel<<<NBLK, 256, 0, stream>>>(y, wv, out);
}